// Round 12
// baseline (499.387 us; speedup 1.0000x reference)
//
#include <hip/hip_runtime.h>

#define Bn 8
#define Nn 4096
#define Pn 4096
#define Kn 32
#define Cn 128

using float4v = __attribute__((ext_vector_type(4))) float;
using short8  = __attribute__((ext_vector_type(8))) short;

__device__ __forceinline__ unsigned short bf16b(float f) {
  union { float f; unsigned u; } v; v.f = f;
  unsigned r = v.u + 0x7FFFu + ((v.u >> 16) & 1u);   // round-nearest-even
  return (unsigned short)(r >> 16);
}

// (hi16(x)) | (hi16(y)<<16) — truncating f32->bf16 pair pack, one v_perm_b32
__device__ __forceinline__ unsigned pkhi(float x, float y) {
  return __builtin_amdgcn_perm(__float_as_uint(y), __float_as_uint(x), 0x07060302u);
}

// ---------------------------------------------------------------------------
// mega: the whole pipeline in ONE dispatch. Rounds 0-11 showed a constant
// ~85 us of non-fused time (prep + finalize + 3 inter-dispatch gaps) vs a
// ~105 us fused interior — merging attacks the larger term.
//   - blocks 0-63: WlT transpose (release-inc ctrs[0]); blocks 64-95: xyz
//     copy; overlapped with every block's nlds/af setup + phase B of ct=0
//     (which doesn't need WlT). Spin on ctrs[0] only before phase A of ct=0.
//   - R7-verified interior verbatim (register-gather ring, two-sided XOR
//     swizzle, setprio): bit-identical numerics to all passing rounds.
//   - epilogue: stats -> gacc (device-scope atomics), release-inc ctrs[1],
//     spin to 1024, then LN+ReLU applied to accs STILL IN REGISTERS, single
//     store (kills finalize dispatch + its 32 MB round-trip).
// Co-residency of all 1024 blocks is guaranteed: launch_bounds(256,4) caps
// VGPR<=128 and LDS=29.95KB<=40KB -> 4 blocks/CU x 256 CU = 1024 -> the
// atomic spin barriers cannot deadlock. rocprof replay without the memset
// only over-satisfies the spin targets (no hang; profile-pass values don't
// feed verification).
// ---------------------------------------------------------------------------
__global__ __launch_bounds__(256, 4) void mega(
    const float* __restrict__ points, const float* __restrict__ lc,
    const int* __restrict__ nl, const int* __restrict__ didx,
    const float* __restrict__ Ww, const float* __restrict__ bwv,
    const float* __restrict__ Wl, const float* __restrict__ blv,
    const float* __restrict__ gamma, const float* __restrict__ beta,
    const float* __restrict__ xyz, float* __restrict__ out,
    unsigned short* __restrict__ WlT, float* __restrict__ gacc,
    unsigned* __restrict__ ctrs) {
  __shared__ unsigned short Mlds[32 * 256];   // 16 KB, two-sided XOR swizzle
  __shared__ int nlds[32 * 32];               // 4 KB, pre-shifted byte offsets
  __shared__ float red[256];                  // 1 KB
  __shared__ unsigned short tile[128 * 33];   // 8.25 KB (prep transpose)

  const int t = threadIdx.x, lane = t & 63, w = t >> 6;
  const int l15 = lane & 15, q = lane >> 4;
  const int blk = blockIdx.x;
  const int b = blk & 7;                      // XCD-affine batch
  const int pg = blk >> 3;                    // 0..127
  const int p0 = pg * 32;
  const int db = didx[b];
  const char* __restrict__ pbase = (const char*)(points + (size_t)db * Nn * Cn);
  float* __restrict__ xout = out + (size_t)Bn * Pn * 3;

  // stage neighbor ids, pre-shifted to byte row offsets (row stride 512 B)
  {
    int4 nv = *(const int4*)(nl + (size_t)(db * Pn + p0) * Kn + t * 4);
    nv.x <<= 9; nv.y <<= 9; nv.z <<= 9; nv.w <<= 9;
    *(int4*)&nlds[t * 4] = nv;
  }

  // ---- distributed prep (overlapped with setup + phase B of ct=0) ----
  if (blk < 64) {
    // transpose 32 k-rows of Wl into WlT (bf16)
#pragma unroll
    for (int i = 0; i < 16; ++i) {
      int idx = i * 256 + t;                  // 0..4095
      int kl = idx >> 7, n = idx & 127;
      tile[n * 33 + kl] = bf16b(Wl[(size_t)(blk * 32 + kl) * 128 + n]);
    }
    __syncthreads();
#pragma unroll
    for (int i = 0; i < 16; ++i) {
      int idx = i * 256 + t;
      int n = idx >> 5, kl = idx & 31;
      WlT[(size_t)n * 2048 + blk * 32 + kl] = tile[n * 33 + kl];
    }
    __syncthreads();   // drains the WlT stores (vmcnt) for all 256 threads
    if (t == 0)
      __hip_atomic_fetch_add(&ctrs[0], 1u, __ATOMIC_RELEASE,
                             __HIP_MEMORY_SCOPE_AGENT);
  } else if (blk < 96) {
    const int i0 = (blk - 64) * 3072 + t * 12;   // 32 blocks x 3072 f32
#pragma unroll
    for (int i = 0; i < 3; ++i)
      *(float4v*)(out + i0 + i * 4) = *(const float4v*)(xyz + i0 + i * 4);
  }

  const float Ww0 = Ww[l15], Ww1 = Ww[16 + l15], Ww2 = Ww[32 + l15];
  const float bw0 = bwv[l15];

  // weight A-frags for my 8 points: A[m=w_out=l15][k=q*8+j]
  short8 af[8];
#pragma unroll
  for (int i = 0; i < 8; ++i) {
    const int p = p0 + w * 8 + i;
    const int pk = (db * Pn + p) * Kn;
    const float* __restrict__ lcp = lc + (size_t)(pk + q * 8) * 3;
    float la[24];
#pragma unroll
    for (int v = 0; v < 6; ++v) *(float4v*)&la[v * 4] = *(const float4v*)(lcp + v * 4);
#pragma unroll
    for (int j = 0; j < 8; ++j) {
      float ww = bw0 + la[3 * j] * Ww0 + la[3 * j + 1] * Ww1 + la[3 * j + 2] * Ww2;
      af[i][j] = (short)bf16b(ww);
    }
  }

  float4v acc[2][2];
#pragma unroll
  for (int pt = 0; pt < 2; ++pt)
#pragma unroll
    for (int nt = 0; nt < 2; ++nt) acc[pt][nt] = (float4v){0.f, 0.f, 0.f, 0.f};

  __syncthreads();   // nlds ready

  // my n-slice: channels w*32 .. w*32+31
  const unsigned short* __restrict__ bpt =
      WlT + (size_t)(w * 32 + l15) * 2048 + q * 8;
  const unsigned cvoff = (unsigned)(l15 * 4);

// issue 8 gathers for point (i), chunk (ct) into fdst[8]
#define ISSUE(i, ct, fdst)                                                 \
  {                                                                        \
    const int pi_ = w * 8 + (i);                                           \
    int nk_[8];                                                            \
    *(int4*)&nk_[0] = *(const int4*)&nlds[pi_ * 32 + q * 8];               \
    *(int4*)&nk_[4] = *(const int4*)&nlds[pi_ * 32 + q * 8 + 4];           \
    _Pragma("unroll") for (int j = 0; j < 8; ++j)                          \
        fdst[j] = *(const float*)(pbase + ((unsigned)nk_[j] + cvoff +      \
                                           (unsigned)((ct) * 64)));        \
  }

// pack + step1 MFMA + two-sided-swizzled ds_write for point (i)
#define FIN(i, fsrc)                                                       \
  {                                                                        \
    const int pi_ = w * 8 + (i);                                           \
    union { short8 s; unsigned u[4]; } bv_;                                \
    bv_.u[0] = pkhi(fsrc[0], fsrc[1]);                                     \
    bv_.u[1] = pkhi(fsrc[2], fsrc[3]);                                     \
    bv_.u[2] = pkhi(fsrc[4], fsrc[5]);                                     \
    bv_.u[3] = pkhi(fsrc[6], fsrc[7]);                                     \
    float4v d_ = {0.f, 0.f, 0.f, 0.f};                                     \
    d_ = __builtin_amdgcn_mfma_f32_16x16x32_bf16(af[i], bv_.s, d_, 0, 0, 0); \
    const unsigned off_ = (unsigned)(pi_ * 512 + ((l15 * 32 + q * 8) ^     \
        ((((pi_ & 7) ^ (l15 & 7)) & 7) << 4)));                            \
    uint2 u_;                                                              \
    u_.x = pkhi(d_[0], d_[1]);                                             \
    u_.y = pkhi(d_[2], d_[3]);                                             \
    *(uint2*)((char*)Mlds + off_) = u_;                                    \
  }

  float fb[4][8];   // 4-point lookahead ring (static indices)

  for (int ct = 0; ct < 8; ++ct) {
    // ---- phase B: step1 — M tiles for my 8 points, c-range [ct*16,+16)
    ISSUE(0, ct, fb[0])
    ISSUE(1, ct, fb[1])
    ISSUE(2, ct, fb[2])
    ISSUE(3, ct, fb[3])
#pragma unroll
    for (int i = 0; i < 8; ++i) {
      FIN(i, fb[i & 3])
      if (i + 4 < 8) ISSUE(i + 4, ct, fb[i & 3])
    }
    __syncthreads();
    if (ct == 0) {
      // WlT must be complete before the first phase A (device-scope acquire)
      if (t == 0) {
        while (__hip_atomic_load(&ctrs[0], __ATOMIC_ACQUIRE,
                                 __HIP_MEMORY_SCOPE_AGENT) < 64u)
          __builtin_amdgcn_s_sleep(2);
      }
      __syncthreads();
    }
    // ---- phase A: step2 — Y += Mchunk @ WlT-chunk for my 32 channels
    const unsigned short* __restrict__ bp = bpt + ct * 256;
    __builtin_amdgcn_s_setprio(1);
#pragma unroll
    for (int ks = 0; ks < 8; ++ks) {
      const unsigned ax = (unsigned)((ks * 64 + q * 16) ^
          ((((l15 & 7) ^ ((ks * 2 + (q >> 1)) & 7)) & 7) << 4));
      short8 a0 = *(const short8*)((const char*)Mlds + l15 * 512 + ax);
      short8 a1 = *(const short8*)((const char*)Mlds + (16 + l15) * 512 + ax);
      short8 b0 = *(const short8*)(bp + ks * 32);
      short8 b1 = *(const short8*)(bp + 32768 + ks * 32);
      acc[0][0] = __builtin_amdgcn_mfma_f32_16x16x32_bf16(a0, b0, acc[0][0], 0, 0, 0);
      acc[0][1] = __builtin_amdgcn_mfma_f32_16x16x32_bf16(a0, b1, acc[0][1], 0, 0, 0);
      acc[1][0] = __builtin_amdgcn_mfma_f32_16x16x32_bf16(a1, b0, acc[1][0], 0, 0, 0);
      acc[1][1] = __builtin_amdgcn_mfma_f32_16x16x32_bf16(a1, b1, acc[1][1], 0, 0, 0);
    }
    __builtin_amdgcn_s_setprio(0);
    __syncthreads();
  }
#undef ISSUE
#undef FIN

  // ---- stats epilogue: disjoint per-wave channel sums -> gacc atomics ----
#pragma unroll
  for (int nt = 0; nt < 2; ++nt) {
    const int ch = w * 32 + nt * 16 + l15;
    const float bb = blv[ch];
    float s = 0.f, sq = 0.f;
#pragma unroll
    for (int pt = 0; pt < 2; ++pt)
#pragma unroll
      for (int r = 0; r < 4; ++r) {
        float v = acc[pt][nt][r] + bb; s += v; sq += v * v;
      }
    s += __shfl_xor(s, 16); s += __shfl_xor(s, 32);
    sq += __shfl_xor(sq, 16); sq += __shfl_xor(sq, 32);
    if (lane < 16) { red[ch] = s; red[128 + ch] = sq; }
  }
  __syncthreads();
  atomicAdd(&gacc[t], red[t]);
  __syncthreads();   // drain the atomic before release
  if (t == 0)
    __hip_atomic_fetch_add(&ctrs[1], 1u, __ATOMIC_RELEASE,
                           __HIP_MEMORY_SCOPE_AGENT);
  if (t == 0) {
    while (__hip_atomic_load(&ctrs[1], __ATOMIC_ACQUIRE,
                             __HIP_MEMORY_SCOPE_AGENT) < 1024u)
      __builtin_amdgcn_s_sleep(4);
  }
  __syncthreads();

  // ---- LN + ReLU applied to accs in registers; single store ----
  const float inv = 1.f / 32768.f;
#pragma unroll
  for (int nt = 0; nt < 2; ++nt) {
    const int ch = w * 32 + nt * 16 + l15;
    const float bb = blv[ch];
    const float g1 = __hip_atomic_load(&gacc[ch], __ATOMIC_RELAXED,
                                       __HIP_MEMORY_SCOPE_AGENT);
    const float g2 = __hip_atomic_load(&gacc[128 + ch], __ATOMIC_RELAXED,
                                       __HIP_MEMORY_SCOPE_AGENT);
    const float mean = g1 * inv;
    const float var = g2 * inv - mean * mean;
    const float scale = rsqrtf(var + 1e-5f) * gamma[ch];
    const float shift = beta[ch] - mean * scale;
#pragma unroll
    for (int pt = 0; pt < 2; ++pt) {
      float4v o;
#pragma unroll
      for (int r = 0; r < 4; ++r)
        o[r] = fmaxf((acc[pt][nt][r] + bb) * scale + shift, 0.f);
      *(float4v*)(xout + ((size_t)(b * Cn + ch)) * Pn + p0 + pt * 16 + q * 4) = o;
    }
  }
}

extern "C" void kernel_launch(void* const* d_in, const int* in_sizes, int n_in,
                              void* d_out, int out_size, void* d_ws, size_t ws_size,
                              hipStream_t stream) {
  const float* xyz    = (const float*)d_in[0];
  const float* points = (const float*)d_in[1];
  const float* lc     = (const float*)d_in[2];
  const int*   nl     = (const int*)d_in[3];
  const int*   didx   = (const int*)d_in[4];
  const float* Ww     = (const float*)d_in[5];
  const float* bw     = (const float*)d_in[6];
  const float* Wl     = (const float*)d_in[7];
  const float* bl     = (const float*)d_in[8];
  const float* gamma  = (const float*)d_in[9];
  const float* beta   = (const float*)d_in[10];

  float* out  = (float*)d_out;
  unsigned short* WlT = (unsigned short*)d_ws;                        // 512 KB
  float* gacc = (float*)((char*)d_ws + (size_t)512 * 1024);           // 1 KB
  unsigned* ctrs = (unsigned*)((char*)d_ws + (size_t)512 * 1024 + 1024);

  // zero gacc + spin counters each launch (graph-capturable memset node)
  hipMemsetAsync((char*)d_ws + (size_t)512 * 1024, 0, 1024 + 64, stream);
  mega<<<1024, 256, 0, stream>>>(points, lc, nl, didx, Ww, bw, Wl, bl,
                                 gamma, beta, xyz, out, WlT, gacc, ctrs);
}

// Round 13
// 197.369 us; speedup vs baseline: 2.5302x; 2.5302x over previous
//
#include <hip/hip_runtime.h>

#define Bn 8
#define Nn 4096
#define Pn 4096
#define Kn 32
#define Cn 128

using float4v = __attribute__((ext_vector_type(4))) float;
using short8  = __attribute__((ext_vector_type(8))) short;

__device__ __forceinline__ unsigned short bf16b(float f) {
  union { float f; unsigned u; } v; v.f = f;
  unsigned r = v.u + 0x7FFFu + ((v.u >> 16) & 1u);   // round-nearest-even
  return (unsigned short)(r >> 16);
}

// (hi16(x)) | (hi16(y)<<16) — truncating f32->bf16 pair pack, one v_perm_b32
__device__ __forceinline__ unsigned pkhi(float x, float y) {
  return __builtin_amdgcn_perm(__float_as_uint(y), __float_as_uint(x), 0x07060302u);
}

// ---------------------------------------------------------------------------
// fused: R7 interior VERBATIM (105.7 us verified) + prep merged in.
//   - blocks 0-63: Wl->WlT transpose, then agent-scope RELEASE inc ctrs[0]
//     (emits L2 writeback — R12-proven correct protocol). blocks 64-95: xyz
//     copy into d_out.
//   - all blocks: spin on ctrs[0]>=64 ONLY before the first phase A (phase B
//     of ct=0 needs no WlT and hides the wait). 64-target counter, t==0-only
//     pollers with s_sleep: satisfied in ~10 us — NOT the R12 storm (that
//     was the 1024-target END barrier + gacc atomic storm, now removed:
//     finalize_ln stays a separate dispatch).
//   - gacc zeroing via hipMemsetAsync (graph-safe, R12-proven).
// Net: 3 dispatches -> 2 (saves prep dispatch + one gap ~= 12 us of the ~33
// us attackable non-fused time; fixed ~52 us harness overhead untouchable).
// ---------------------------------------------------------------------------
__global__ __launch_bounds__(256, 4) void fused(
    const float* __restrict__ points, const float* __restrict__ lc,
    const int* __restrict__ nl, const int* __restrict__ didx,
    const float* __restrict__ Ww, const float* __restrict__ bwv,
    const float* __restrict__ Wl, const float* __restrict__ blv,
    const float* __restrict__ xyz, float* __restrict__ out,
    unsigned short* __restrict__ WlT, float* __restrict__ gacc,
    unsigned* __restrict__ ctrs) {
  __shared__ unsigned short Mlds[32 * 256];   // 16 KB, two-sided XOR swizzle
  __shared__ unsigned short tile[128 * 33];   // 8.25 KB (prep transpose only)
  __shared__ int nlds[32 * 32];               // 4 KB, pre-shifted byte offsets
  __shared__ float red[256];                  // 1 KB   (total ~29.9 KB)

  const int t = threadIdx.x, lane = t & 63, w = t >> 6;
  const int l15 = lane & 15, q = lane >> 4;
  const int blk = blockIdx.x;
  const int b = blk & 7;                      // XCD-affine batch
  const int pg = blk >> 3;                    // 0..127
  const int p0 = pg * 32;
  const int db = didx[b];
  const char* __restrict__ pbase = (const char*)(points + (size_t)db * Nn * Cn);
  float* __restrict__ xout = out + (size_t)Bn * Pn * 3;

  // stage neighbor ids, pre-shifted to byte row offsets (row stride 512 B)
  {
    int4 nv = *(const int4*)(nl + (size_t)(db * Pn + p0) * Kn + t * 4);
    nv.x <<= 9; nv.y <<= 9; nv.z <<= 9; nv.w <<= 9;
    *(int4*)&nlds[t * 4] = nv;
  }

  // ---- distributed prep (overlapped with af setup + phase B of ct=0) ----
  if (blk < 64) {
#pragma unroll
    for (int i = 0; i < 16; ++i) {
      int idx = i * 256 + t;                  // 0..4095
      int kl = idx >> 7, n = idx & 127;
      tile[n * 33 + kl] = bf16b(Wl[(size_t)(blk * 32 + kl) * 128 + n]);
    }
    __syncthreads();
#pragma unroll
    for (int i = 0; i < 16; ++i) {
      int idx = i * 256 + t;
      int n = idx >> 5, kl = idx & 31;
      WlT[(size_t)n * 2048 + blk * 32 + kl] = tile[n * 33 + kl];
    }
    __syncthreads();   // all 256 threads' WlT stores drained (vmcnt)
    if (t == 0)
      __hip_atomic_fetch_add(&ctrs[0], 1u, __ATOMIC_RELEASE,
                             __HIP_MEMORY_SCOPE_AGENT);
  } else if (blk < 96) {
    const int i0 = (blk - 64) * 3072 + t * 12;   // 32 blocks x 3072 f32
#pragma unroll
    for (int i = 0; i < 3; ++i)
      *(float4v*)(out + i0 + i * 4) = *(const float4v*)(xyz + i0 + i * 4);
  }

  const float Ww0 = Ww[l15], Ww1 = Ww[16 + l15], Ww2 = Ww[32 + l15];
  const float bw0 = bwv[l15];

  // weight A-frags for my 8 points: A[m=w_out=l15][k=q*8+j]
  short8 af[8];
#pragma unroll
  for (int i = 0; i < 8; ++i) {
    const int p = p0 + w * 8 + i;
    const int pk = (db * Pn + p) * Kn;
    const float* __restrict__ lcp = lc + (size_t)(pk + q * 8) * 3;
    float la[24];
#pragma unroll
    for (int v = 0; v < 6; ++v) *(float4v*)&la[v * 4] = *(const float4v*)(lcp + v * 4);
#pragma unroll
    for (int j = 0; j < 8; ++j) {
      float ww = bw0 + la[3 * j] * Ww0 + la[3 * j + 1] * Ww1 + la[3 * j + 2] * Ww2;
      af[i][j] = (short)bf16b(ww);
    }
  }

  float4v acc[2][2];
#pragma unroll
  for (int pt = 0; pt < 2; ++pt)
#pragma unroll
    for (int nt = 0; nt < 2; ++nt) acc[pt][nt] = (float4v){0.f, 0.f, 0.f, 0.f};

  __syncthreads();   // nlds ready

  // my n-slice: channels w*32 .. w*32+31
  const unsigned short* __restrict__ bpt =
      WlT + (size_t)(w * 32 + l15) * 2048 + q * 8;
  const unsigned cvoff = (unsigned)(l15 * 4);

// issue 8 gathers for point (i), chunk (ct) into fdst[8]
#define ISSUE(i, ct, fdst)                                                 \
  {                                                                        \
    const int pi_ = w * 8 + (i);                                           \
    int nk_[8];                                                            \
    *(int4*)&nk_[0] = *(const int4*)&nlds[pi_ * 32 + q * 8];               \
    *(int4*)&nk_[4] = *(const int4*)&nlds[pi_ * 32 + q * 8 + 4];           \
    _Pragma("unroll") for (int j = 0; j < 8; ++j)                          \
        fdst[j] = *(const float*)(pbase + ((unsigned)nk_[j] + cvoff +      \
                                           (unsigned)((ct) * 64)));        \
  }

// pack + step1 MFMA + two-sided-swizzled ds_write for point (i)
#define FIN(i, fsrc)                                                       \
  {                                                                        \
    const int pi_ = w * 8 + (i);                                           \
    union { short8 s; unsigned u[4]; } bv_;                                \
    bv_.u[0] = pkhi(fsrc[0], fsrc[1]);                                     \
    bv_.u[1] = pkhi(fsrc[2], fsrc[3]);                                     \
    bv_.u[2] = pkhi(fsrc[4], fsrc[5]);                                     \
    bv_.u[3] = pkhi(fsrc[6], fsrc[7]);                                     \
    float4v d_ = {0.f, 0.f, 0.f, 0.f};                                     \
    d_ = __builtin_amdgcn_mfma_f32_16x16x32_bf16(af[i], bv_.s, d_, 0, 0, 0); \
    const unsigned off_ = (unsigned)(pi_ * 512 + ((l15 * 32 + q * 8) ^     \
        ((((pi_ & 7) ^ (l15 & 7)) & 7) << 4)));                            \
    uint2 u_;                                                              \
    u_.x = pkhi(d_[0], d_[1]);                                             \
    u_.y = pkhi(d_[2], d_[3]);                                             \
    *(uint2*)((char*)Mlds + off_) = u_;                                    \
  }

  float fb[4][8];   // 4-point lookahead ring (static indices)

  for (int ct = 0; ct < 8; ++ct) {
    // ---- phase B: step1 — M tiles for my 8 points, c-range [ct*16,+16)
    ISSUE(0, ct, fb[0])
    ISSUE(1, ct, fb[1])
    ISSUE(2, ct, fb[2])
    ISSUE(3, ct, fb[3])
#pragma unroll
    for (int i = 0; i < 8; ++i) {
      FIN(i, fb[i & 3])
      if (i + 4 < 8) ISSUE(i + 4, ct, fb[i & 3])
    }
    __syncthreads();
    if (ct == 0) {
      // WlT must be complete before the first phase A (agent-scope acquire)
      if (t == 0) {
        while (__hip_atomic_load(&ctrs[0], __ATOMIC_ACQUIRE,
                                 __HIP_MEMORY_SCOPE_AGENT) < 64u)
          __builtin_amdgcn_s_sleep(4);
      }
      __syncthreads();
    }
    // ---- phase A: step2 — Y += Mchunk @ WlT-chunk for my 32 channels
    const unsigned short* __restrict__ bp = bpt + ct * 256;
    __builtin_amdgcn_s_setprio(1);
#pragma unroll
    for (int ks = 0; ks < 8; ++ks) {
      const unsigned ax = (unsigned)((ks * 64 + q * 16) ^
          ((((l15 & 7) ^ ((ks * 2 + (q >> 1)) & 7)) & 7) << 4));
      short8 a0 = *(const short8*)((const char*)Mlds + l15 * 512 + ax);
      short8 a1 = *(const short8*)((const char*)Mlds + (16 + l15) * 512 + ax);
      short8 b0 = *(const short8*)(bp + ks * 32);
      short8 b1 = *(const short8*)(bp + 32768 + ks * 32);
      acc[0][0] = __builtin_amdgcn_mfma_f32_16x16x32_bf16(a0, b0, acc[0][0], 0, 0, 0);
      acc[0][1] = __builtin_amdgcn_mfma_f32_16x16x32_bf16(a0, b1, acc[0][1], 0, 0, 0);
      acc[1][0] = __builtin_amdgcn_mfma_f32_16x16x32_bf16(a1, b0, acc[1][0], 0, 0, 0);
      acc[1][1] = __builtin_amdgcn_mfma_f32_16x16x32_bf16(a1, b1, acc[1][1], 0, 0, 0);
    }
    __builtin_amdgcn_s_setprio(0);
    __syncthreads();
  }
#undef ISSUE
#undef FIN

  // epilogue: bias, transposed store (B,C,P), disjoint per-wave channel stats
#pragma unroll
  for (int nt = 0; nt < 2; ++nt) {
    const int ch = w * 32 + nt * 16 + l15;
    const float bb = blv[ch];
    float s = 0.f, sq = 0.f;
#pragma unroll
    for (int pt = 0; pt < 2; ++pt) {
      float4v o;
#pragma unroll
      for (int r = 0; r < 4; ++r) {
        float v = acc[pt][nt][r] + bb; o[r] = v; s += v; sq += v * v;
      }
      *(float4v*)(xout + ((size_t)(b * Cn + ch)) * Pn + p0 + pt * 16 + q * 4) = o;
    }
    s += __shfl_xor(s, 16); s += __shfl_xor(s, 32);
    sq += __shfl_xor(sq, 16); sq += __shfl_xor(sq, 32);
    if (lane < 16) { red[ch] = s; red[128 + ch] = sq; }
  }
  __syncthreads();
  atomicAdd(&gacc[t], red[t]);
}

// ---------------------------------------------------------------------------
// finalize: layernorm (per-channel over B*P) + relu, in place on x chunk
// ---------------------------------------------------------------------------
__global__ __launch_bounds__(256) void finalize_ln(float* __restrict__ x,
                                                   const float* __restrict__ gacc,
                                                   const float* __restrict__ gamma,
                                                   const float* __restrict__ beta) {
  const int idx = blockIdx.x * 256 + threadIdx.x;
  const int fi = idx * 4;
  const int c = (fi >> 12) & 127;
  const float inv = 1.f / 32768.f;
  const float mean = gacc[c] * inv;
  const float var = gacc[128 + c] * inv - mean * mean;
  const float scale = rsqrtf(var + 1e-5f) * gamma[c];
  const float shift = beta[c] - mean * scale;
  float4v v = *(float4v*)(x + fi);
#pragma unroll
  for (int r = 0; r < 4; ++r) v[r] = fmaxf(v[r] * scale + shift, 0.f);
  *(float4v*)(x + fi) = v;
}

extern "C" void kernel_launch(void* const* d_in, const int* in_sizes, int n_in,
                              void* d_out, int out_size, void* d_ws, size_t ws_size,
                              hipStream_t stream) {
  const float* xyz    = (const float*)d_in[0];
  const float* points = (const float*)d_in[1];
  const float* lc     = (const float*)d_in[2];
  const int*   nl     = (const int*)d_in[3];
  const int*   didx   = (const int*)d_in[4];
  const float* Ww     = (const float*)d_in[5];
  const float* bw     = (const float*)d_in[6];
  const float* Wl     = (const float*)d_in[7];
  const float* bl     = (const float*)d_in[8];
  const float* gamma  = (const float*)d_in[9];
  const float* beta   = (const float*)d_in[10];

  float* out  = (float*)d_out;
  float* xout = out + (size_t)Bn * Pn * 3;                       // x chunk (B,C,P)
  unsigned short* WlT = (unsigned short*)d_ws;                   // 512 KB
  float* gacc = (float*)((char*)d_ws + (size_t)512 * 1024);      // 1 KB
  unsigned* ctrs = (unsigned*)((char*)d_ws + (size_t)512 * 1024 + 1024);

  // zero gacc + spin counter (graph-capturable memset node; R12-proven)
  hipMemsetAsync((char*)d_ws + (size_t)512 * 1024, 0, 1024 + 64, stream);
  fused<<<1024, 256, 0, stream>>>(points, lc, nl, didx, Ww, bw, Wl, bl,
                                  xyz, out, WlT, gacc, ctrs);
  finalize_ln<<<4096, 256, 0, stream>>>(xout, gacc, gamma, beta);
}